// Round 1
// baseline (3038.763 us; speedup 1.0000x reference)
//
#include <hip/hip_runtime.h>
#include <hip/hip_bf16.h>
#include <math.h>

// Problem constants
#define BB 8
#define CC 64
#define HH 256
#define WW 256
#define SS 512
#define LIN_SCALE 0.044194173824159216f   // 1/sqrt(512)
#define CONV_SCALE 0.041666666666666664f  // 1/sqrt(64*9)
#define SQRT2 1.4142135623730951f

// ---------------------------------------------------------------------------
// Small kernels
// ---------------------------------------------------------------------------

// repack OIHW [cout][cin][3][3] -> [cin][k][cout]
__global__ void repack_w_k(const float* __restrict__ w, float* __restrict__ p) {
    int i = blockIdx.x * 256 + threadIdx.x;          // over 64*64*9 = 36864
    if (i >= CC * CC * 9) return;
    int cout = i / (CC * 9);
    int rem  = i - cout * (CC * 9);
    int cin  = rem / 9;
    int k    = rem - cin * 9;
    p[(cin * 9 + k) * CC + cout] = w[i];
}

// s[b][cin] = sum_j style[b][j]*mod_w[cin][j]*LIN_SCALE + mod_b[cin]
__global__ void style_s_k(const float* __restrict__ style, const float* __restrict__ mod_w,
                          const float* __restrict__ mod_b, float* __restrict__ sbuf) {
    int tid = threadIdx.x;                            // 512 threads
    int b = tid >> 6, cin = tid & 63;
    float acc = 0.f;
    for (int j = 0; j < SS; ++j)
        acc += style[b * SS + j] * mod_w[cin * SS + j];
    sbuf[b * CC + cin] = acc * LIN_SCALE + mod_b[cin];
}

// demod[b][cout] = rsqrt(sum_{cin,k} (CONV_SCALE*conv_w*s)^2 + 1e-8)
__global__ void demod_k(const float* __restrict__ conv_w, const float* __restrict__ sbuf,
                        float* __restrict__ demod) {
    int tid = threadIdx.x;                            // 512 threads
    int b = tid >> 6, cout = tid & 63;
    float sum = 0.f;
    for (int cin = 0; cin < CC; ++cin) {
        float m = CONV_SCALE * sbuf[b * CC + cin];
        const float* wp = conv_w + (cout * CC + cin) * 9;
        #pragma unroll
        for (int k = 0; k < 9; ++k) { float v = wp[k] * m; sum += v * v; }
    }
    demod[b * CC + cout] = 1.0f / sqrtf(sum + 1e-8f);
}

// packed modulated weights: pmw[b][(cin*9+k)*64 + cout]
__global__ void packmod_k(const float* __restrict__ conv_w, const float* __restrict__ sbuf,
                          const float* __restrict__ demod, float* __restrict__ pmw) {
    int i = blockIdx.x * 256 + threadIdx.x;           // over 8*36864
    if (i >= BB * CC * CC * 9) return;
    int b = i / (CC * CC * 9);
    int r = i - b * (CC * CC * 9);
    int cout = r / (CC * 9);
    int rem  = r - cout * (CC * 9);
    int cin  = rem / 9;
    int k    = rem - cin * 9;
    float v = CONV_SCALE * conv_w[r] * sbuf[b * CC + cin] * demod[b * CC + cout];
    pmw[b * (CC * CC * 9) + (cin * 9 + k) * CC + cout] = v;
}

// ---------------------------------------------------------------------------
// Direct 3x3 conv, C=64 -> C=64, SAME padding.
// Tile: 64(x) x 4(y) pixels, all 64 couts. 256 threads.
// Thread: 8 couts x 8 pixels (64 fp32 acc). 8-cin LDS staging.
// EPI: 0 = PReLU(aux=alpha[64]), 1 = +residual(aux=plane, may alias out),
//      2 = fused leaky-relu (aux=bias[64]).
// PERB: per-batch weights (modulated conv).
// ---------------------------------------------------------------------------
template <int EPI, int PERB>
__global__ __launch_bounds__(256, 2)
void conv3x3_k(const float* __restrict__ in, const float* __restrict__ wp,
               const float* aux, float* out) {
    __shared__ __align__(16) float sIn[8 * 6 * 72];   // 8 cins x 6 rows x 72 pitch
    __shared__ __align__(16) float sW[8 * 9 * 64];    // 8 cins x 9 k x 64 couts

    const int tid = threadIdx.x;
    const int blk = blockIdx.x;
    const int b     = blk >> 8;
    const int t     = blk & 255;
    const int tileY = t >> 2;       // 64 tiles of 4 rows
    const int tileX = t & 3;        // 4 tiles of 64 cols
    const int y0 = tileY * 4;
    const int x0 = tileX * 64;

    const int cg  = tid & 7;        // cout group (8 couts)
    const int pg  = tid >> 3;
    const int tx8 = pg & 7;         // x octet
    const int ty  = pg >> 3;        // row in tile (0..3)
    const int xb  = tx8 * 8;

    float acc[8][8];
    #pragma unroll
    for (int q = 0; q < 8; ++q)
        #pragma unroll
        for (int p = 0; p < 8; ++p) acc[q][p] = 0.f;

    const float* wbase = wp + (PERB ? (size_t)b * (CC * CC * 9) : 0);

    for (int cin0 = 0; cin0 < CC; cin0 += 8) {
        __syncthreads();
        // ---- stage input tile (with halo, zero-padded) ----
        for (int j = tid; j < 8 * 6 * 72; j += 256) {
            int ci  = j / 432;              // 6*72
            int rem = j - ci * 432;
            int row = rem / 72;
            int xx  = rem - row * 72;
            float v = 0.f;
            if (xx < 66) {
                int gy = y0 - 1 + row;
                int gx = x0 - 1 + xx;
                if ((unsigned)gy < 256u && (unsigned)gx < 256u)
                    v = in[(((size_t)(b * CC + cin0 + ci)) << 16) + (gy << 8) + gx];
            }
            sIn[j] = v;
        }
        // ---- stage weights [ci][k][cout] (already packed contiguously) ----
        {
            const float* wsrc = wbase + cin0 * 576;
            for (int j = tid; j < 4608; j += 256) sW[j] = wsrc[j];
        }
        __syncthreads();

        #pragma unroll
        for (int ci = 0; ci < 8; ++ci) {
            float r0[10], r1[10], r2[10];
            const float* base = &sIn[ci * 432 + ty * 72 + xb];
            #pragma unroll
            for (int j = 0; j < 10; ++j) {
                r0[j] = base[j];
                r1[j] = base[72 + j];
                r2[j] = base[144 + j];
            }
            #pragma unroll
            for (int k = 0; k < 9; ++k) {
                float w[8];
                #pragma unroll
                for (int q = 0; q < 8; ++q) w[q] = sW[ci * 576 + k * 64 + cg * 8 + q];
                #pragma unroll
                for (int q = 0; q < 8; ++q)
                    #pragma unroll
                    for (int p = 0; p < 8; ++p) {
                        float iv = (k < 3) ? r0[p + k] : (k < 6) ? r1[p + (k - 3)] : r2[p + (k - 6)];
                        acc[q][p] = fmaf(iv, w[q], acc[q][p]);
                    }
            }
        }
    }

    // ---- epilogue + store ----
    const int oy = y0 + ty;
    const int ox = x0 + xb;
    #pragma unroll
    for (int q = 0; q < 8; ++q) {
        const int co = cg * 8 + q;
        const size_t obase = (((size_t)(b * CC + co)) << 16) + (oy << 8) + ox;
        float v[8];
        #pragma unroll
        for (int p = 0; p < 8; ++p) v[p] = acc[q][p];
        if (EPI == 0) {
            const float a = aux[co];
            #pragma unroll
            for (int p = 0; p < 8; ++p) v[p] = v[p] > 0.f ? v[p] : a * v[p];
        } else if (EPI == 1) {
            #pragma unroll
            for (int p = 0; p < 8; ++p) v[p] += aux[obase + p];
        } else {
            const float bia = aux[co];
            #pragma unroll
            for (int p = 0; p < 8; ++p) {
                float ob = v[p] + bia;
                v[p] = (ob > 0.f ? ob : 0.2f * ob) * SQRT2;
            }
        }
        float4 s0 = make_float4(v[0], v[1], v[2], v[3]);
        float4 s1 = make_float4(v[4], v[5], v[6], v[7]);
        *reinterpret_cast<float4*>(out + obase) = s0;
        *reinterpret_cast<float4*>(out + obase + 4) = s1;
    }
}

// ---------------------------------------------------------------------------
// Host launch
// ---------------------------------------------------------------------------
extern "C" void kernel_launch(void* const* d_in, const int* in_sizes, int n_in,
                              void* d_out, int out_size, void* d_ws, size_t ws_size,
                              hipStream_t stream) {
    const float* x       = (const float*)d_in[0];
    const float* style   = (const float*)d_in[1];
    const float* w1a     = (const float*)d_in[2];
    const float* alpha1  = (const float*)d_in[3];
    const float* w1b     = (const float*)d_in[4];
    const float* w2a     = (const float*)d_in[5];
    const float* alpha2  = (const float*)d_in[6];
    const float* w2b     = (const float*)d_in[7];
    const float* mod_w   = (const float*)d_in[8];
    const float* mod_b   = (const float*)d_in[9];
    const float* conv_w  = (const float*)d_in[10];
    const float* fused_b = (const float*)d_in[11];
    float* out = (float*)d_out;

    const size_t PLANE = (size_t)BB * CC * HH * WW;   // 33,554,432 floats
    const size_t WSZ   = (size_t)CC * CC * 9;         // 36,864 floats

    float* ws = (float*)d_ws;
    float* sbuf  = ws;                    // 512
    float* demod = sbuf + 512;            // 512
    float* pw1a  = demod + 512;           // 4 packed shared weights
    float* pw1b  = pw1a + WSZ;
    float* pw2a  = pw1b + WSZ;
    float* pw2b  = pw2a + WSZ;
    float* pmw   = pw2b + WSZ;            // 8 * WSZ (per-batch modulated)
    float* planeA = pmw + BB * WSZ;

    const size_t small_floats = (size_t)(planeA - ws);
    const size_t need2 = (small_floats + 2 * PLANE) * sizeof(float);

    float* A = planeA;
    float* Bp;
    bool need_copy;
    if (ws_size >= need2) {
        Bp = planeA + PLANE;   // both planes in workspace; conv5 writes d_out
        need_copy = false;
    } else {
        Bp = out;              // use d_out as scratch plane; conv5 -> A, then copy
        need_copy = true;
    }

    // --- weight preprocessing ---
    const int RP_BLOCKS = (CC * CC * 9 + 255) / 256;
    hipLaunchKernelGGL(repack_w_k, dim3(RP_BLOCKS), dim3(256), 0, stream, w1a, pw1a);
    hipLaunchKernelGGL(repack_w_k, dim3(RP_BLOCKS), dim3(256), 0, stream, w1b, pw1b);
    hipLaunchKernelGGL(repack_w_k, dim3(RP_BLOCKS), dim3(256), 0, stream, w2a, pw2a);
    hipLaunchKernelGGL(repack_w_k, dim3(RP_BLOCKS), dim3(256), 0, stream, w2b, pw2b);
    hipLaunchKernelGGL(style_s_k, dim3(1), dim3(512), 0, stream, style, mod_w, mod_b, sbuf);
    hipLaunchKernelGGL(demod_k, dim3(1), dim3(512), 0, stream, conv_w, sbuf, demod);
    const int PM_BLOCKS = (BB * CC * CC * 9 + 255) / 256;
    hipLaunchKernelGGL(packmod_k, dim3(PM_BLOCKS), dim3(256), 0, stream, conv_w, sbuf, demod, pmw);

    // --- conv chain ---
    const dim3 cgrid(BB * 256), cblk(256);
    // 1: t1 = prelu(conv(x, w1a))            -> A
    hipLaunchKernelGGL((conv3x3_k<0, 0>), cgrid, cblk, 0, stream, x, pw1a, alpha1, A);
    // 2: h1 = x + conv(t1, w1b)              -> B
    hipLaunchKernelGGL((conv3x3_k<1, 0>), cgrid, cblk, 0, stream, A, pw1b, x, Bp);
    // 3: t2 = prelu(conv(h1, w2a))           -> A
    hipLaunchKernelGGL((conv3x3_k<0, 0>), cgrid, cblk, 0, stream, Bp, pw2a, alpha2, A);
    // 4: h2 = h1 + conv(t2, w2b)             -> B (in-place residual: same-index r/w)
    hipLaunchKernelGGL((conv3x3_k<1, 0>), cgrid, cblk, 0, stream, A, pw2b, Bp, Bp);
    // 5: out = fused_lrelu(modconv(h2) + b)
    if (!need_copy) {
        hipLaunchKernelGGL((conv3x3_k<2, 1>), cgrid, cblk, 0, stream, Bp, pmw, fused_b, out);
    } else {
        hipLaunchKernelGGL((conv3x3_k<2, 1>), cgrid, cblk, 0, stream, Bp, pmw, fused_b, A);
        hipMemcpyAsync(out, A, PLANE * sizeof(float), hipMemcpyDeviceToDevice, stream);
    }
}

// Round 2
// 909.181 us; speedup vs baseline: 3.3423x; 3.3423x over previous
//
#include <hip/hip_runtime.h>
#include <hip/hip_bf16.h>
#include <math.h>

#define BB 8
#define CC 64
#define HH 256
#define WW 256
#define SS 512
#define LIN_SCALE 0.044194173824159216f   // 1/sqrt(512)
#define CONV_SCALE 0.041666666666666664f  // 1/sqrt(64*9)
#define SQRT2 1.4142135623730951f

typedef __attribute__((ext_vector_type(8))) short short8;
typedef __attribute__((ext_vector_type(16))) float f32x16;

// ---------------------------------------------------------------------------
// helpers: fp32 -> (hi, lo) bf16 split, RNE
// ---------------------------------------------------------------------------
__device__ __forceinline__ unsigned bf16rne_u(float v) {
    unsigned u = __float_as_uint(v);
    return (u + 0x7fffu + ((u >> 16) & 1u)) >> 16;
}
__device__ __forceinline__ void split1(float v, unsigned& h, unsigned& l) {
    h = bf16rne_u(v);
    float hf = __uint_as_float(h << 16);
    l = bf16rne_u(v - hf);
}

// ---------------------------------------------------------------------------
// prep kernels
// ---------------------------------------------------------------------------

// NCHW -> channels-last [b][y][x][c] fp32 (64x64 LDS tile transpose, +1 pad)
__global__ __launch_bounds__(256) void tocl_k(const float* __restrict__ x, float* __restrict__ o) {
    __shared__ float tile[64][65];
    const int blk = blockIdx.x;                 // 8 * 256 * 4 = 8192
    const int b = blk >> 10;
    const int rem = blk & 1023;
    const int y = rem >> 2;
    const int x0 = (rem & 3) << 6;
    const int tid = threadIdx.x;
    const int lane = tid & 63, g = tid >> 6;
    const float* xb = x + ((size_t)b << 22) + (y << 8) + x0;
    #pragma unroll
    for (int i = 0; i < 16; ++i) {
        int c = i * 4 + g;
        tile[c][lane] = xb[((size_t)c << 16) + lane];
    }
    __syncthreads();
    float* ob = o + ((size_t)b << 22) + (((size_t)(y << 8) + x0) << 6);
    #pragma unroll
    for (int i = 0; i < 16; ++i) {
        int xx = i * 4 + g;
        ob[(xx << 6) + lane] = tile[lane][xx];
    }
}

// pack fixed conv weight OIHW fp32 -> [tap][cout][cin] bf16 hi/lo
__global__ void packw_k(const float* __restrict__ w, ushort* __restrict__ pH, ushort* __restrict__ pL) {
    int i = blockIdx.x * 256 + threadIdx.x;
    if (i >= CC * CC * 9) return;
    int co = i / 576;
    int rem = i - co * 576;
    int ci = rem / 9;
    int t = rem - ci * 9;
    unsigned h, l; split1(w[i], h, l);
    int d = (t * 64 + co) * 64 + ci;
    pH[d] = (ushort)h; pL[d] = (ushort)l;
}

// s[b][cin]
__global__ void style_s_k(const float* __restrict__ style, const float* __restrict__ mod_w,
                          const float* __restrict__ mod_b, float* __restrict__ sbuf) {
    int tid = threadIdx.x;  // 512
    int b = tid >> 6, cin = tid & 63;
    float acc = 0.f;
    for (int j = 0; j < SS; ++j) acc += style[b * SS + j] * mod_w[cin * SS + j];
    sbuf[b * CC + cin] = acc * LIN_SCALE + mod_b[cin];
}

// demod[b][cout]
__global__ void demod_k(const float* __restrict__ conv_w, const float* __restrict__ sbuf,
                        float* __restrict__ demod) {
    int tid = threadIdx.x;  // 512
    int b = tid >> 6, cout = tid & 63;
    float sum = 0.f;
    for (int cin = 0; cin < CC; ++cin) {
        float m = CONV_SCALE * sbuf[b * CC + cin];
        const float* wp = conv_w + (cout * CC + cin) * 9;
        #pragma unroll
        for (int k = 0; k < 9; ++k) { float v = wp[k] * m; sum += v * v; }
    }
    demod[b * CC + cout] = 1.0f / sqrtf(sum + 1e-8f);
}

// per-batch modulated weights -> [b][tap][cout][cin] bf16 hi/lo
__global__ void packmod_k(const float* __restrict__ conv_w, const float* __restrict__ sbuf,
                          const float* __restrict__ demod, ushort* __restrict__ pH,
                          ushort* __restrict__ pL) {
    int i = blockIdx.x * 256 + threadIdx.x;
    if (i >= BB * CC * CC * 9) return;
    int b = i / 36864;
    int r = i - b * 36864;
    int co = r / 576;
    int rem = r - co * 576;
    int ci = rem / 9;
    int t = rem - ci * 9;
    float v = CONV_SCALE * conv_w[r] * sbuf[b * CC + ci] * demod[b * CC + co];
    unsigned h, l; split1(v, h, l);
    int d = b * 36864 + (t * 64 + co) * 64 + ci;
    pH[d] = (ushort)h; pL[d] = (ushort)l;
}

// ---------------------------------------------------------------------------
// MFMA conv: 3x3, C64->C64, SAME. Input channels-last fp32 [b][y][x][64].
// Block: 8 rows x 32 cols, 4 waves; wave = 2 rows (2 N-frags of 32 px),
// 2 M-frags of 32 couts. K chunked 16 cins through LDS (hi/lo bf16 split).
// Per nominal product, 3 MFMA terms: Ah*Bh + Ah*Bl + Al*Bh.
// EPI: 0 = PReLU -> CL out; 1 = +resid(CL, may alias out) -> CL out;
//      2 = fused leaky-relu -> NCHW out.  PERB: per-batch weights.
// ---------------------------------------------------------------------------
template <int EPI, int PERB>
__global__ __launch_bounds__(256, 2)
void mconv3x3_k(const float* __restrict__ in, const ushort* __restrict__ wH,
                const ushort* __restrict__ wL, const float* aux, float* out) {
    __shared__ __align__(16) ushort sInH[340 * 16];   // [10 rows][34 x][16 c], swizzled
    __shared__ __align__(16) ushort sInL[340 * 16];
    __shared__ __align__(16) ushort sWH[9 * 64 * 16]; // [tap][cout][16 c], swizzled
    __shared__ __align__(16) ushort sWL[9 * 64 * 16];

    const int tid = threadIdx.x;
    const int blk = blockIdx.x;
    const int b  = blk >> 8;
    const int tt = blk & 255;
    const int ty = tt >> 3, tx = tt & 7;
    const int y0 = ty * 8, x0 = tx * 32;
    const int wv = tid >> 6, l = tid & 63, ln = l & 31, lh = l >> 5;

    const float* inb = in + ((size_t)b << 22);
    const ushort* wHb = wH + (PERB ? b * 36864 : 0);
    const ushort* wLb = wL + (PERB ? b * 36864 : 0);

    f32x16 acc[2][2];
    #pragma unroll
    for (int m = 0; m < 2; ++m)
        #pragma unroll
        for (int j = 0; j < 2; ++j) acc[m][j] = (f32x16)(0.0f);

    for (int c0 = 0; c0 < 64; c0 += 16) {
        __syncthreads();
        // ---- stage input chunk: 340 px x 2 halves ----
        for (int jj = tid; jj < 680; jj += 256) {
            int p = jj >> 1, h = jj & 1;
            int rr = p / 34, xx = p - rr * 34;
            int gy = y0 - 1 + rr, gx = x0 - 1 + xx;
            float v[8];
            if ((unsigned)gy < 256u && (unsigned)gx < 256u) {
                const float4* gp = (const float4*)(inb + (((size_t)(gy << 8) + gx) << 6) + c0 + h * 8);
                float4 a = gp[0], c = gp[1];
                v[0] = a.x; v[1] = a.y; v[2] = a.z; v[3] = a.w;
                v[4] = c.x; v[5] = c.y; v[6] = c.z; v[7] = c.w;
            } else {
                #pragma unroll
                for (int i = 0; i < 8; ++i) v[i] = 0.f;
            }
            unsigned hh[8], ll[8];
            #pragma unroll
            for (int i = 0; i < 8; ++i) split1(v[i], hh[i], ll[i]);
            int base = p * 16 + ((h ^ ((p >> 2) & 1)) << 3);
            uint4 Hv = make_uint4(hh[0] | (hh[1] << 16), hh[2] | (hh[3] << 16),
                                  hh[4] | (hh[5] << 16), hh[6] | (hh[7] << 16));
            uint4 Lv = make_uint4(ll[0] | (ll[1] << 16), ll[2] | (ll[3] << 16),
                                  ll[4] | (ll[5] << 16), ll[6] | (ll[7] << 16));
            *(uint4*)(&sInH[base]) = Hv;
            *(uint4*)(&sInL[base]) = Lv;
        }
        // ---- stage weight chunk: 9 taps x 64 couts x 2 halves ----
        for (int jj = tid; jj < 1152; jj += 256) {
            int idx = jj >> 1, h = jj & 1;
            int t = idx >> 6, co = idx & 63;
            int gsrc = (t * 64 + co) * 64 + c0 + h * 8;
            int dst = (t * 64 + co) * 16 + ((h ^ ((co >> 2) & 1)) << 3);
            *(uint4*)(&sWH[dst]) = *(const uint4*)(&wHb[gsrc]);
            *(uint4*)(&sWL[dst]) = *(const uint4*)(&wLb[gsrc]);
        }
        __syncthreads();

        #pragma unroll
        for (int t = 0; t < 9; ++t) {
            const int dy = t / 3 - 1, dx = t % 3 - 1;
            short8 aH[2], aL[2], bH[2], bL[2];
            #pragma unroll
            for (int m = 0; m < 2; ++m) {
                int co = m * 32 + ln;
                int off = (t * 64 + co) * 16 + ((lh ^ ((co >> 2) & 1)) << 3);
                aH[m] = *(const short8*)(&sWH[off]);
                aL[m] = *(const short8*)(&sWL[off]);
            }
            #pragma unroll
            for (int j = 0; j < 2; ++j) {
                int rr = 2 * wv + j + dy + 1;
                int xx = ln + dx + 1;
                int p = rr * 34 + xx;
                int off = p * 16 + ((lh ^ ((p >> 2) & 1)) << 3);
                bH[j] = *(const short8*)(&sInH[off]);
                bL[j] = *(const short8*)(&sInL[off]);
            }
            #pragma unroll
            for (int m = 0; m < 2; ++m)
                #pragma unroll
                for (int j = 0; j < 2; ++j) {
                    acc[m][j] = __builtin_amdgcn_mfma_f32_32x32x16_bf16(aH[m], bH[j], acc[m][j], 0, 0, 0);
                    acc[m][j] = __builtin_amdgcn_mfma_f32_32x32x16_bf16(aH[m], bL[j], acc[m][j], 0, 0, 0);
                    acc[m][j] = __builtin_amdgcn_mfma_f32_32x32x16_bf16(aL[m], bH[j], acc[m][j], 0, 0, 0);
                }
        }
    }

    // ---- epilogue ----
    // C/D: col = ln (pixel), row = (r&3) + 8*(r>>2) + 4*lh  (+ 32*m)
    float* outb = out + ((size_t)b << 22);
    const float* residb = aux + ((size_t)b << 22);   // EPI==1 only
    #pragma unroll
    for (int m = 0; m < 2; ++m)
        #pragma unroll
        for (int j = 0; j < 2; ++j) {
            const int yo = y0 + 2 * wv + j;
            #pragma unroll
            for (int q = 0; q < 4; ++q) {
                const int co0 = m * 32 + 8 * q + 4 * lh;
                float4 v = make_float4(acc[m][j][4 * q + 0], acc[m][j][4 * q + 1],
                                       acc[m][j][4 * q + 2], acc[m][j][4 * q + 3]);
                const size_t claddr = (((size_t)(yo << 8) + x0 + ln) << 6) + co0;
                if (EPI == 0) {
                    float4 al = *(const float4*)(aux + co0);
                    v.x = v.x > 0.f ? v.x : al.x * v.x;
                    v.y = v.y > 0.f ? v.y : al.y * v.y;
                    v.z = v.z > 0.f ? v.z : al.z * v.z;
                    v.w = v.w > 0.f ? v.w : al.w * v.w;
                    *(float4*)(outb + claddr) = v;
                } else if (EPI == 1) {
                    float4 r = *(const float4*)(residb + claddr);
                    v.x += r.x; v.y += r.y; v.z += r.z; v.w += r.w;
                    *(float4*)(outb + claddr) = v;
                } else {
                    float4 bi = *(const float4*)(aux + co0);
                    float ob;
                    ob = v.x + bi.x; v.x = (ob > 0.f ? ob : 0.2f * ob) * SQRT2;
                    ob = v.y + bi.y; v.y = (ob > 0.f ? ob : 0.2f * ob) * SQRT2;
                    ob = v.z + bi.z; v.z = (ob > 0.f ? ob : 0.2f * ob) * SQRT2;
                    ob = v.w + bi.w; v.w = (ob > 0.f ? ob : 0.2f * ob) * SQRT2;
                    const size_t pix = (size_t)(yo << 8) + x0 + ln;
                    outb[((size_t)(co0 + 0) << 16) + pix] = v.x;
                    outb[((size_t)(co0 + 1) << 16) + pix] = v.y;
                    outb[((size_t)(co0 + 2) << 16) + pix] = v.z;
                    outb[((size_t)(co0 + 3) << 16) + pix] = v.w;
                }
            }
        }
}

// ---------------------------------------------------------------------------
// Host launch
// ---------------------------------------------------------------------------
extern "C" void kernel_launch(void* const* d_in, const int* in_sizes, int n_in,
                              void* d_out, int out_size, void* d_ws, size_t ws_size,
                              hipStream_t stream) {
    const float* x       = (const float*)d_in[0];
    const float* style   = (const float*)d_in[1];
    const float* w1a     = (const float*)d_in[2];
    const float* alpha1  = (const float*)d_in[3];
    const float* w1b     = (const float*)d_in[4];
    const float* w2a     = (const float*)d_in[5];
    const float* alpha2  = (const float*)d_in[6];
    const float* w2b     = (const float*)d_in[7];
    const float* mod_w   = (const float*)d_in[8];
    const float* mod_b   = (const float*)d_in[9];
    const float* conv_w  = (const float*)d_in[10];
    const float* fused_b = (const float*)d_in[11];
    float* out = (float*)d_out;

    const size_t PLANE = (size_t)BB * CC * HH * WW;   // 33,554,432 floats
    const size_t WUS   = 36864;                       // ushorts per packed weight plane

    char* ws = (char*)d_ws;
    float*  sbuf  = (float*)(ws);                       // 512 f
    float*  demod = (float*)(ws + 2048);                // 512 f
    ushort* pw    = (ushort*)(ws + 4096);               // 8 x 36864 ushort
    ushort* pw1aH = pw + 0 * WUS, *pw1aL = pw + 1 * WUS;
    ushort* pw1bH = pw + 2 * WUS, *pw1bL = pw + 3 * WUS;
    ushort* pw2aH = pw + 4 * WUS, *pw2aL = pw + 5 * WUS;
    ushort* pw2bH = pw + 6 * WUS, *pw2bL = pw + 7 * WUS;
    ushort* pmwH  = pw + 8 * WUS;                       // 8 batches
    ushort* pmwL  = pmwH + BB * WUS;
    char*   planes = (char*)(pmwL + BB * WUS);          // 16B-aligned (offset 1,773,568)

    const size_t small_bytes = (size_t)(planes - ws);
    const size_t need3 = small_bytes + 3 * PLANE * sizeof(float);
    const size_t need2 = small_bytes + 2 * PLANE * sizeof(float);

    float* P0 = (float*)planes;
    float* P2 = P0 + PLANE;
    float* P1;
    if (ws_size >= need3)      P1 = P2 + PLANE;
    else                       P1 = out;   // CL scratch; conv5 overwrites out (NCHW) last
    (void)need2;

    // --- prep ---
    hipLaunchKernelGGL(tocl_k, dim3(BB * 1024), dim3(256), 0, stream, x, P0);
    const int PK_BLOCKS = (CC * CC * 9 + 255) / 256;
    hipLaunchKernelGGL(packw_k, dim3(PK_BLOCKS), dim3(256), 0, stream, w1a, pw1aH, pw1aL);
    hipLaunchKernelGGL(packw_k, dim3(PK_BLOCKS), dim3(256), 0, stream, w1b, pw1bH, pw1bL);
    hipLaunchKernelGGL(packw_k, dim3(PK_BLOCKS), dim3(256), 0, stream, w2a, pw2aH, pw2aL);
    hipLaunchKernelGGL(packw_k, dim3(PK_BLOCKS), dim3(256), 0, stream, w2b, pw2bH, pw2bL);
    hipLaunchKernelGGL(style_s_k, dim3(1), dim3(512), 0, stream, style, mod_w, mod_b, sbuf);
    hipLaunchKernelGGL(demod_k, dim3(1), dim3(512), 0, stream, conv_w, sbuf, demod);
    const int PM_BLOCKS = (BB * CC * CC * 9 + 255) / 256;
    hipLaunchKernelGGL(packmod_k, dim3(PM_BLOCKS), dim3(256), 0, stream, conv_w, sbuf, demod, pmwH, pmwL);

    // --- conv chain (all channels-last except final NCHW write) ---
    const dim3 cgrid(BB * 256), cblk(256);
    // c1: t1 = prelu(conv(x, w1a))            P0 -> P1
    hipLaunchKernelGGL((mconv3x3_k<0, 0>), cgrid, cblk, 0, stream, P0, pw1aH, pw1aL, alpha1, P1);
    // c2: h1 = x + conv(t1, w1b)              P1 -> P2  (resid P0)
    hipLaunchKernelGGL((mconv3x3_k<1, 0>), cgrid, cblk, 0, stream, P1, pw1bH, pw1bL, P0, P2);
    // c3: t2 = prelu(conv(h1, w2a))           P2 -> P0
    hipLaunchKernelGGL((mconv3x3_k<0, 0>), cgrid, cblk, 0, stream, P2, pw2aH, pw2aL, alpha2, P0);
    // c4: h2 = h1 + conv(t2, w2b)             P0 -> P2  (resid P2, same-index r/w: safe)
    hipLaunchKernelGGL((mconv3x3_k<1, 0>), cgrid, cblk, 0, stream, P0, pw2bH, pw2bL, P2, P2);
    // c5: out = fused_lrelu(modconv(h2) + b)  P2 -> out (NCHW)
    hipLaunchKernelGGL((mconv3x3_k<2, 1>), cgrid, cblk, 0, stream, P2, pmwH, pmwL, fused_b, out);
}